// Round 6
// baseline (483.435 us; speedup 1.0000x reference)
//
#include <hip/hip_runtime.h>
#include <hip/hip_bf16.h>
#include <math.h>

// Problem constants (from reference)
constexpr int kN2 = 180224, kN1 = 11264, kN0 = 1024;
constexpr int kE1 = 168960, kE2 = 10240;
constexpr int kIN = 602, kHID = 256, kOUT = 41;
constexpr int kKP = 608;  // kIN padded to multiple of 32 (MFMA K)

typedef __attribute__((ext_vector_type(8))) short bf16x8;
typedef __attribute__((ext_vector_type(4))) float f32x4;

static __device__ __forceinline__ ushort f2bf(float v) {
    return __bfloat16_as_ushort(__float2bfloat16(v));
}

// ---------------------------------------------------------------------------
// CSR build, both edge lists in one launch each: histogram -> scan -> bucket.
// ---------------------------------------------------------------------------
__global__ __launch_bounds__(256)
void hist_both_kernel(const int* __restrict__ dst1, const int* __restrict__ dst2,
                      int* __restrict__ cnt1, int* __restrict__ cnt2) {
    const int gid = blockIdx.x * 256 + threadIdx.x;
    if (gid < kE1) {
        atomicAdd(&cnt1[dst1[gid]], 1);
    } else if (gid < kE1 + kE2) {
        atomicAdd(&cnt2[dst2[gid - kE1]], 1);
    }
}

// block 0 scans cnt1[kN1] -> off1; block 1 scans cnt2[kN0] -> off2
__global__ __launch_bounds__(256)
void scan_both_kernel(const int* __restrict__ cnt1, int* __restrict__ off1,
                      const int* __restrict__ cnt2, int* __restrict__ off2) {
    __shared__ int part[256];
    const int t = threadIdx.x;
    const int* cnt = blockIdx.x ? cnt2 : cnt1;
    int* off = blockIdx.x ? off2 : off1;
    const int nN = blockIdx.x ? kN0 : kN1;
    const int CH = nN >> 8;
    const int base = t * CH;
    int s = 0;
    for (int i = 0; i < CH; ++i) s += cnt[base + i];
    part[t] = s;
    __syncthreads();
    for (int ofs = 1; ofs < 256; ofs <<= 1) {
        int v = (t >= ofs) ? part[t - ofs] : 0;
        __syncthreads();
        if (t >= ofs) part[t] += v;
        __syncthreads();
    }
    int run = (t == 0) ? 0 : part[t - 1];
    for (int i = 0; i < CH; ++i) {
        off[base + i] = run;
        run += cnt[base + i];
    }
    if (t == 255) off[nN] = run;
}

__global__ __launch_bounds__(256)
void bucket_both_kernel(const int* __restrict__ src1, const int* __restrict__ dst1,
                        const int* __restrict__ off1, int* __restrict__ cur1,
                        int* __restrict__ ebuf1,
                        const int* __restrict__ src2, const int* __restrict__ dst2,
                        const int* __restrict__ off2, int* __restrict__ cur2,
                        int* __restrict__ ebuf2) {
    const int gid = blockIdx.x * 256 + threadIdx.x;
    if (gid < kE1) {
        const int d = dst1[gid];
        const int p = atomicAdd(&cur1[d], 1);
        ebuf1[off1[d] + p] = src1[gid];
    } else if (gid < kE1 + kE2) {
        const int e = gid - kE1;
        const int d = dst2[e];
        const int p = atomicAdd(&cur2[d], 1);
        ebuf2[off2[d] + p] = src2[e];
    }
}

// ---------------------------------------------------------------------------
// Aggregation layer 1: block per dst node, float2 loads, 2-edge unroll,
// fp32 accumulate, packed bf16 mean store into padded [kN1][608] buffer.
// (unchanged from R5)
// ---------------------------------------------------------------------------
__global__ __launch_bounds__(128)
void aggregate1_kernel(const float* __restrict__ x, const int* __restrict__ off,
                       const int* __restrict__ ebuf, ushort* __restrict__ aggb) {
    const int d = blockIdx.x;
    const int t = threadIdx.x;
    const int b = off[d], e = off[d + 1];
    float p0x = 0.f, p0y = 0.f, p1x = 0.f, p1y = 0.f, p2x = 0.f, p2y = 0.f;
    float q0x = 0.f, q0y = 0.f, q1x = 0.f, q1y = 0.f, q2x = 0.f, q2y = 0.f;
    int i = b;
    for (; i + 2 <= e; i += 2) {
        const int s0 = ebuf[i], s1 = ebuf[i + 1];
        const float2* r0 = (const float2*)(x + (size_t)s0 * kIN);
        const float2* r1 = (const float2*)(x + (size_t)s1 * kIN);
        const float2 a0 = r0[t], a1 = r0[t + 128];
        const float2 b0 = r1[t], b1 = r1[t + 128];
        p0x += a0.x; p0y += a0.y; p1x += a1.x; p1y += a1.y;
        q0x += b0.x; q0y += b0.y; q1x += b1.x; q1y += b1.y;
        if (t < 45) {
            const float2 a2 = r0[t + 256], b2 = r1[t + 256];
            p2x += a2.x; p2y += a2.y; q2x += b2.x; q2y += b2.y;
        }
    }
    if (i < e) {
        const int s0 = ebuf[i];
        const float2* r0 = (const float2*)(x + (size_t)s0 * kIN);
        const float2 a0 = r0[t], a1 = r0[t + 128];
        p0x += a0.x; p0y += a0.y; p1x += a1.x; p1y += a1.y;
        if (t < 45) {
            const float2 a2 = r0[t + 256];
            p2x += a2.x; p2y += a2.y;
        }
    }
    p0x += q0x; p0y += q0y; p1x += q1x; p1y += q1y; p2x += q2x; p2y += q2y;
    const float inv = 1.0f / fmaxf((float)(e - b), 1.0f);
    uint* ar = (uint*)(aggb + (size_t)d * kKP);  // 304 uints per row
    ar[t]       = (uint)f2bf(p0x * inv) | ((uint)f2bf(p0y * inv) << 16);
    ar[t + 128] = (uint)f2bf(p1x * inv) | ((uint)f2bf(p1y * inv) << 16);
    if (t < 45) ar[t + 256] = (uint)f2bf(p2x * inv) | ((uint)f2bf(p2y * inv) << 16);
    if (t >= 45 && t < 48) ar[t + 256] = 0u;  // zero pad shorts 602..607
}

// ---------------------------------------------------------------------------
// Convert x[:N1] fp32 [kN1][602] -> bf16 [kN1][608]; flat uint-task grid.
// ---------------------------------------------------------------------------
__global__ __launch_bounds__(256)
void conv_x1_kernel(const float* __restrict__ x, ushort* __restrict__ xb) {
    const int task = blockIdx.x * 256 + threadIdx.x;  // row*304 + u
    const int row = task / 304;
    const int u = task - row * 304;
    uint v = 0u;
    if (u < 301) {
        const float2 f = *(const float2*)(x + (size_t)row * kIN + 2 * u);
        v = (uint)f2bf(f.x) | ((uint)f2bf(f.y) << 16);
    }
    ((uint*)xb)[task] = v;
}

// Convert+transpose both W1 [602][256] -> Wt bf16 [256][608]; grid 512.
__global__ __launch_bounds__(256)
void conv_w_both_kernel(const float* __restrict__ W1l, const float* __restrict__ W1r,
                        ushort* __restrict__ wlt, ushort* __restrict__ wrt) {
    const int which = blockIdx.x >> 8;
    const int j = blockIdx.x & 255;
    const float* W = which ? W1r : W1l;
    ushort* Wt = which ? wrt : wlt;
    for (int k = threadIdx.x; k < kKP; k += 256) {
        float v = (k < kIN) ? W[(size_t)k * kHID + j] : 0.f;
        Wt[(size_t)j * kKP + k] = f2bf(v);
    }
}

// ---------------------------------------------------------------------------
// Layer-1 GEMM via MFMA -- DIAGNOSTIC BUILD (kREP=4).
// The staged K-pipeline runs 4 identical passes accumulating into the same
// acc (4S), scaled by 0.25f before bias (exact up to ~2 ulp). This makes the
// kernel's unit cost visible: total_delta = 3 * L1, and if 4*L1 > ~255us the
// kernel enters the rocprof top-5 with full counters. Structure per-step is
// identical to R5: stage(next) -> ds_read frags -> 16 MFMA -> barrier.
// ---------------------------------------------------------------------------
constexpr int kNT = kKP / 32;  // 19 K-steps
constexpr int kREP = 4;        // diagnostic repeat factor

__global__ __launch_bounds__(256)
void layer1_mfma(const ushort* __restrict__ aggb, const ushort* __restrict__ xb,
                 const ushort* __restrict__ wlt, const ushort* __restrict__ wrt,
                 const float* __restrict__ b1, float* __restrict__ h) {
    __shared__ ushort buf[2][1280 * 8];  // 2 x 20KB
    const int t = threadIdx.x;
    const int lane = t & 63, wid = t >> 6;
    const int bid = blockIdx.x;
    const int n0 = (bid >> 1) * 32;
    const int j0 = (bid & 1) * 128;

    f32x4 acc[2][2];
#pragma unroll
    for (int m = 0; m < 2; ++m)
#pragma unroll
        for (int n = 0; n < 2; ++n) acc[m][n] = (f32x4){0.f, 0.f, 0.f, 0.f};

    // stage K-step kt into buf[db]: 1280 16B chunks = 20 wave-stripes of 64
    auto stage = [&](int kt, int db) {
        const int k0 = kt * 32;
#pragma unroll
        for (int i = 0; i < 5; ++i) {
            const int stripe = i * 4 + wid;
            const int c = stripe * 64 + lane;
            const ushort* g;
            if (c < 256) {  // A: mat(1b) x row(5b) x slot(2b)
                const int mat = c >> 7, r = (c >> 2) & 31, slot = c & 3;
                const int k8 = slot ^ ((r >> 1) & 3);
                g = (mat ? xb : aggb) + (size_t)(n0 + r) * kKP + k0 + k8 * 8;
            } else {        // B: mat(1b) x row(7b) x slot(2b)
                const int c2 = c - 256;
                const int mat = c2 >> 9, rb = (c2 >> 2) & 127, slot = c2 & 3;
                const int k8 = slot ^ ((rb >> 1) & 3);
                g = (mat ? wrt : wlt) + (size_t)(j0 + rb) * kKP + k0 + k8 * 8;
            }
            __builtin_amdgcn_global_load_lds(
                (const __attribute__((address_space(1))) void*)g,
                (__attribute__((address_space(3))) void*)&buf[db][stripe * 512],
                16, 0, 0);
        }
    };

    stage(0, 0);
    __syncthreads();

    const int rl = lane & 15;
    const int k8r = lane >> 4;
    int db = 0;
    constexpr int kTOT = kNT * kREP;  // 76 steps total (4 passes over K)
    for (int s = 0; s < kTOT; ++s) {
        if (s + 1 < kTOT) {
            const int kt_next = (s + 1) % kNT;
            stage(kt_next, db ^ 1);
        }

        bf16x8 af[2][2], bfr[2][2];
#pragma unroll
        for (int m = 0; m < 2; ++m)
#pragma unroll
            for (int p = 0; p < 2; ++p) {
                const int r = m * 16 + rl;
                const int slot = k8r ^ ((r >> 1) & 3);
                const int c = p * 128 + r * 4 + slot;
                af[m][p] = *(const bf16x8*)&buf[db][c * 8];
            }
#pragma unroll
        for (int n = 0; n < 2; ++n)
#pragma unroll
            for (int p = 0; p < 2; ++p) {
                const int rb = wid * 32 + n * 16 + rl;
                const int slot = k8r ^ ((rb >> 1) & 3);
                const int c = 256 + p * 512 + rb * 4 + slot;
                bfr[n][p] = *(const bf16x8*)&buf[db][c * 8];
            }
#pragma unroll
        for (int m = 0; m < 2; ++m)
#pragma unroll
            for (int n = 0; n < 2; ++n) {
                acc[m][n] = __builtin_amdgcn_mfma_f32_16x16x32_bf16(
                    af[m][0], bfr[n][0], acc[m][n], 0, 0, 0);
                acc[m][n] = __builtin_amdgcn_mfma_f32_16x16x32_bf16(
                    af[m][1], bfr[n][1], acc[m][n], 0, 0, 0);
            }
        __syncthreads();  // drains stage(next); protects buf reuse
        db ^= 1;
    }

    const float scale = 1.0f / (float)kREP;  // 0.25f, exact power of two
    const int col_l = lane & 15, rq = lane >> 4;
#pragma unroll
    for (int m = 0; m < 2; ++m)
#pragma unroll
        for (int n = 0; n < 2; ++n) {
            const int gc = j0 + wid * 32 + n * 16 + col_l;
            const float bias = b1[gc];
#pragma unroll
            for (int q = 0; q < 4; ++q) {
                const int gr = n0 + m * 16 + rq * 4 + q;
                h[(size_t)gr * kHID + gc] =
                    fmaxf(acc[m][n][q] * scale + bias, 0.f);
            }
        }
}

// ---------------------------------------------------------------------------
// Layer 2 fused: gather-mean h[src2] rows (CSR, no atomics) + GEMV + row
// log_softmax. One wave per output node. (unchanged from R5)
// ---------------------------------------------------------------------------
__global__ __launch_bounds__(64)
void layer2_fused(const float* __restrict__ h, const int* __restrict__ off,
                  const int* __restrict__ ebuf, const float* __restrict__ W2l,
                  const float* __restrict__ W2r, const float* __restrict__ b2,
                  float* __restrict__ out) {
    __shared__ float sa[kHID];
    __shared__ float sh[kHID];
    const int n = blockIdx.x;
    const int t = threadIdx.x;
    const int b = off[n], e = off[n + 1];
    float ax = 0.f, ay = 0.f, az = 0.f, aw = 0.f;
    for (int i = b; i < e; ++i) {
        const float4 r = ((const float4*)(h + (size_t)ebuf[i] * kHID))[t];
        ax += r.x; ay += r.y; az += r.z; aw += r.w;
    }
    const float inv = 1.0f / fmaxf((float)(e - b), 1.0f);
    float4 o;
    o.x = ax * inv; o.y = ay * inv; o.z = az * inv; o.w = aw * inv;
    ((float4*)sa)[t] = o;
    ((float4*)sh)[t] = ((const float4*)(h + (size_t)n * kHID))[t];
    __syncthreads();

    float logit = 0.0f;
    if (t < kOUT) {
        logit = b2[t];
        for (int k = 0; k < kHID; ++k)
            logit += sa[k] * W2l[k * kOUT + t] + sh[k] * W2r[k * kOUT + t];
    }
    float m = (t < kOUT) ? logit : -INFINITY;
#pragma unroll
    for (int ofs = 32; ofs >= 1; ofs >>= 1)
        m = fmaxf(m, __shfl_xor(m, ofs));
    float ev = (t < kOUT) ? expf(logit - m) : 0.0f;
    float s = ev;
#pragma unroll
    for (int ofs = 32; ofs >= 1; ofs >>= 1)
        s += __shfl_xor(s, ofs);
    if (t < kOUT)
        out[(size_t)n * kOUT + t] = logit - m - logf(s);
}

// ---------------------------------------------------------------------------
extern "C" void kernel_launch(void* const* d_in, const int* in_sizes, int n_in,
                              void* d_out, int out_size, void* d_ws, size_t ws_size,
                              hipStream_t stream) {
    const float* x    = (const float*)d_in[0];
    const int*   src1 = (const int*)d_in[1];
    const int*   dst1 = (const int*)d_in[2];
    const int*   src2 = (const int*)d_in[3];
    const int*   dst2 = (const int*)d_in[4];
    const float* W1l  = (const float*)d_in[5];
    const float* W1r  = (const float*)d_in[6];
    const float* b1   = (const float*)d_in[7];
    const float* W2l  = (const float*)d_in[8];
    const float* W2r  = (const float*)d_in[9];
    const float* b2   = (const float*)d_in[10];
    float* out = (float*)d_out;

    // ---- workspace layout ----
    int* cnt1 = (int*)d_ws;                  // kN1
    int* cur1 = cnt1 + kN1;                  // kN1
    int* cnt2 = cur1 + kN1;                  // kN0
    int* cur2 = cnt2 + kN0;                  // kN0
    int* off1 = cur2 + kN0;                  // kN1 + 1
    int* off2 = off1 + kN1 + 1;              // kN0 + 1
    int* ebuf1 = off2 + kN0 + 1;             // kE1
    int* ebuf2 = ebuf1 + kE1;                // kE2
    size_t int_words = (size_t)2 * kN1 + 2 * kN0 + (kN1 + 1) + (kN0 + 1) + kE1 + kE2;
    int_words = (int_words + 7) & ~(size_t)7;  // 32B align

    ushort* aggb = (ushort*)((int*)d_ws + int_words);   // kN1*kKP bf16
    ushort* xb   = aggb + (size_t)kN1 * kKP;            // kN1*kKP
    ushort* wlt  = xb + (size_t)kN1 * kKP;              // kHID*kKP
    ushort* wrt  = wlt + (size_t)kHID * kKP;            // kHID*kKP
    float* h     = (float*)(wrt + (size_t)kHID * kKP);  // kN1*kHID fp32

    // zero histogram/cursor region (cnt1,cur1,cnt2,cur2 contiguous)
    hipMemsetAsync(cnt1, 0, ((size_t)2 * kN1 + 2 * kN0) * sizeof(int), stream);

    constexpr int EB = (kE1 + kE2 + 255) / 256;  // 700
    hist_both_kernel<<<EB, 256, 0, stream>>>(dst1, dst2, cnt1, cnt2);
    scan_both_kernel<<<2, 256, 0, stream>>>(cnt1, off1, cnt2, off2);
    bucket_both_kernel<<<EB, 256, 0, stream>>>(src1, dst1, off1, cur1, ebuf1,
                                               src2, dst2, off2, cur2, ebuf2);

    conv_x1_kernel<<<(kN1 * 304) / 256, 256, 0, stream>>>(x, xb);
    conv_w_both_kernel<<<512, 256, 0, stream>>>(W1l, W1r, wlt, wrt);

    aggregate1_kernel<<<kN1, 128, 0, stream>>>(x, off1, ebuf1, aggb);

    layer1_mfma<<<(kN1 / 32) * 2, 256, 0, stream>>>(aggb, xb, wlt, wrt, b1, h);

    layer2_fused<<<kN0, 64, 0, stream>>>(h, off2, ebuf2, W2l, W2r, b2, out);
}

// Round 7
// 205.316 us; speedup vs baseline: 2.3546x; 2.3546x over previous
//
#include <hip/hip_runtime.h>
#include <hip/hip_bf16.h>
#include <math.h>

// Problem constants (from reference)
constexpr int kN2 = 180224, kN1 = 11264, kN0 = 1024;
constexpr int kE1 = 168960, kE2 = 10240;
constexpr int kIN = 602, kHID = 256, kOUT = 41;
constexpr int kKP = 608;  // kIN padded to multiple of 32 (MFMA K)

typedef __attribute__((ext_vector_type(8))) short bf16x8;
typedef __attribute__((ext_vector_type(4))) float f32x4;

static __device__ __forceinline__ ushort f2bf(float v) {
    return __bfloat16_as_ushort(__float2bfloat16(v));
}

// ---------------------------------------------------------------------------
// CSR build, both edge lists in one launch each: histogram -> scan -> bucket.
// ---------------------------------------------------------------------------
__global__ __launch_bounds__(256)
void hist_both_kernel(const int* __restrict__ dst1, const int* __restrict__ dst2,
                      int* __restrict__ cnt1, int* __restrict__ cnt2) {
    const int gid = blockIdx.x * 256 + threadIdx.x;
    if (gid < kE1) {
        atomicAdd(&cnt1[dst1[gid]], 1);
    } else if (gid < kE1 + kE2) {
        atomicAdd(&cnt2[dst2[gid - kE1]], 1);
    }
}

// block 0 scans cnt1[kN1] -> off1; block 1 scans cnt2[kN0] -> off2
__global__ __launch_bounds__(256)
void scan_both_kernel(const int* __restrict__ cnt1, int* __restrict__ off1,
                      const int* __restrict__ cnt2, int* __restrict__ off2) {
    __shared__ int part[256];
    const int t = threadIdx.x;
    const int* cnt = blockIdx.x ? cnt2 : cnt1;
    int* off = blockIdx.x ? off2 : off1;
    const int nN = blockIdx.x ? kN0 : kN1;
    const int CH = nN >> 8;
    const int base = t * CH;
    int s = 0;
    for (int i = 0; i < CH; ++i) s += cnt[base + i];
    part[t] = s;
    __syncthreads();
    for (int ofs = 1; ofs < 256; ofs <<= 1) {
        int v = (t >= ofs) ? part[t - ofs] : 0;
        __syncthreads();
        if (t >= ofs) part[t] += v;
        __syncthreads();
    }
    int run = (t == 0) ? 0 : part[t - 1];
    for (int i = 0; i < CH; ++i) {
        off[base + i] = run;
        run += cnt[base + i];
    }
    if (t == 255) off[nN] = run;
}

__global__ __launch_bounds__(256)
void bucket_both_kernel(const int* __restrict__ src1, const int* __restrict__ dst1,
                        const int* __restrict__ off1, int* __restrict__ cur1,
                        int* __restrict__ ebuf1,
                        const int* __restrict__ src2, const int* __restrict__ dst2,
                        const int* __restrict__ off2, int* __restrict__ cur2,
                        int* __restrict__ ebuf2) {
    const int gid = blockIdx.x * 256 + threadIdx.x;
    if (gid < kE1) {
        const int d = dst1[gid];
        const int p = atomicAdd(&cur1[d], 1);
        ebuf1[off1[d] + p] = src1[gid];
    } else if (gid < kE1 + kE2) {
        const int e = gid - kE1;
        const int d = dst2[e];
        const int p = atomicAdd(&cur2[d], 1);
        ebuf2[off2[d] + p] = src2[e];
    }
}

// ---------------------------------------------------------------------------
// Aggregation layer 1: block per dst node, float2 loads, 2-edge unroll,
// fp32 accumulate, packed bf16 mean store into padded [kN1][608] buffer.
// (unchanged from R5)
// ---------------------------------------------------------------------------
__global__ __launch_bounds__(128)
void aggregate1_kernel(const float* __restrict__ x, const int* __restrict__ off,
                       const int* __restrict__ ebuf, ushort* __restrict__ aggb) {
    const int d = blockIdx.x;
    const int t = threadIdx.x;
    const int b = off[d], e = off[d + 1];
    float p0x = 0.f, p0y = 0.f, p1x = 0.f, p1y = 0.f, p2x = 0.f, p2y = 0.f;
    float q0x = 0.f, q0y = 0.f, q1x = 0.f, q1y = 0.f, q2x = 0.f, q2y = 0.f;
    int i = b;
    for (; i + 2 <= e; i += 2) {
        const int s0 = ebuf[i], s1 = ebuf[i + 1];
        const float2* r0 = (const float2*)(x + (size_t)s0 * kIN);
        const float2* r1 = (const float2*)(x + (size_t)s1 * kIN);
        const float2 a0 = r0[t], a1 = r0[t + 128];
        const float2 b0 = r1[t], b1 = r1[t + 128];
        p0x += a0.x; p0y += a0.y; p1x += a1.x; p1y += a1.y;
        q0x += b0.x; q0y += b0.y; q1x += b1.x; q1y += b1.y;
        if (t < 45) {
            const float2 a2 = r0[t + 256], b2 = r1[t + 256];
            p2x += a2.x; p2y += a2.y; q2x += b2.x; q2y += b2.y;
        }
    }
    if (i < e) {
        const int s0 = ebuf[i];
        const float2* r0 = (const float2*)(x + (size_t)s0 * kIN);
        const float2 a0 = r0[t], a1 = r0[t + 128];
        p0x += a0.x; p0y += a0.y; p1x += a1.x; p1y += a1.y;
        if (t < 45) {
            const float2 a2 = r0[t + 256];
            p2x += a2.x; p2y += a2.y;
        }
    }
    p0x += q0x; p0y += q0y; p1x += q1x; p1y += q1y; p2x += q2x; p2y += q2y;
    const float inv = 1.0f / fmaxf((float)(e - b), 1.0f);
    uint* ar = (uint*)(aggb + (size_t)d * kKP);  // 304 uints per row
    ar[t]       = (uint)f2bf(p0x * inv) | ((uint)f2bf(p0y * inv) << 16);
    ar[t + 128] = (uint)f2bf(p1x * inv) | ((uint)f2bf(p1y * inv) << 16);
    if (t < 45) ar[t + 256] = (uint)f2bf(p2x * inv) | ((uint)f2bf(p2y * inv) << 16);
    if (t >= 45 && t < 48) ar[t + 256] = 0u;  // zero pad shorts 602..607
}

// ---------------------------------------------------------------------------
// Convert x[:N1] fp32 [kN1][602] -> bf16 [kN1][608]; flat uint-task grid.
// ---------------------------------------------------------------------------
__global__ __launch_bounds__(256)
void conv_x1_kernel(const float* __restrict__ x, ushort* __restrict__ xb) {
    const int task = blockIdx.x * 256 + threadIdx.x;  // row*304 + u
    const int row = task / 304;
    const int u = task - row * 304;
    uint v = 0u;
    if (u < 301) {
        const float2 f = *(const float2*)(x + (size_t)row * kIN + 2 * u);
        v = (uint)f2bf(f.x) | ((uint)f2bf(f.y) << 16);
    }
    ((uint*)xb)[task] = v;
}

// Convert+transpose both W1 [602][256] -> Wt bf16 [256][608]; grid 512.
__global__ __launch_bounds__(256)
void conv_w_both_kernel(const float* __restrict__ W1l, const float* __restrict__ W1r,
                        ushort* __restrict__ wlt, ushort* __restrict__ wrt) {
    const int which = blockIdx.x >> 8;
    const int j = blockIdx.x & 255;
    const float* W = which ? W1r : W1l;
    ushort* Wt = which ? wrt : wlt;
    for (int k = threadIdx.x; k < kKP; k += 256) {
        float v = (k < kIN) ? W[(size_t)k * kHID + j] : 0.f;
        Wt[(size_t)j * kKP + k] = f2bf(v);
    }
}

// ---------------------------------------------------------------------------
// Layer-1 GEMM: BARRIER-FREE per-wave MFMA. h = relu(agg@W1l + b1 + x@W1r).
// One wave owns a 32x32 output tile; block = 4 waves as 2x2 (64x64 tile);
// grid = 176 M-tiles x 4 N-tiles = 704 blocks (2816 waves, ~2.75/SIMD).
// No LDS, no __syncthreads: A/B fragments are loaded global->VGPR directly
// (16B/lane bf16x8, same layout validated in R3-R5); B (0.6MB total) stays
// L2-resident and is re-read by all M-tiles. Depth-1 software pipeline with
// two NAMED frag sets (static indexing, rule #20); the compiler is free to
// hoist loads across MFMA since no barrier forces a vmcnt(0) drain.
// Per K-step: 8 loads + 8 MFMA; 19 steps over K=608 for both operand pairs.
// ---------------------------------------------------------------------------
struct L1Frags {
    bf16x8 a[2];   // aggb rows m*16
    bf16x8 xx[2];  // xb rows
    bf16x8 wl[2];  // wlt rows n*16
    bf16x8 wr[2];  // wrt rows
};

__global__ __launch_bounds__(256)
void layer1_wave(const ushort* __restrict__ aggb, const ushort* __restrict__ xb,
                 const ushort* __restrict__ wlt, const ushort* __restrict__ wrt,
                 const float* __restrict__ b1, float* __restrict__ h) {
    const int t = threadIdx.x;
    const int lane = t & 63, wid = t >> 6;
    const int wr_ = wid >> 1, wc = wid & 1;        // 2x2 wave grid
    const int mt = blockIdx.x >> 2, nt = blockIdx.x & 3;
    const int mrow = mt * 64 + wr_ * 32;
    const int jbase = nt * 64 + wc * 32;

    const int rl = lane & 15;
    const int k8 = lane >> 4;

    // lane-constant base pointers (row*kKP + k8*8), rows 16B-aligned
    const ushort* pa0 = aggb + (size_t)(mrow + rl) * kKP + k8 * 8;
    const ushort* pa1 = pa0 + 16 * kKP;
    const ushort* px0 = xb + (size_t)(mrow + rl) * kKP + k8 * 8;
    const ushort* px1 = px0 + 16 * kKP;
    const ushort* pl0 = wlt + (size_t)(jbase + rl) * kKP + k8 * 8;
    const ushort* pl1 = pl0 + 16 * kKP;
    const ushort* pr0 = wrt + (size_t)(jbase + rl) * kKP + k8 * 8;
    const ushort* pr1 = pr0 + 16 * kKP;

    f32x4 acc[2][2];
#pragma unroll
    for (int m = 0; m < 2; ++m)
#pragma unroll
        for (int n = 0; n < 2; ++n) acc[m][n] = (f32x4){0.f, 0.f, 0.f, 0.f};

#define L1_LOAD(F, ks)                                               \
    do {                                                             \
        const int o = (ks) * 32;                                     \
        (F).a[0]  = *(const bf16x8*)(pa0 + o);                       \
        (F).a[1]  = *(const bf16x8*)(pa1 + o);                       \
        (F).xx[0] = *(const bf16x8*)(px0 + o);                       \
        (F).xx[1] = *(const bf16x8*)(px1 + o);                       \
        (F).wl[0] = *(const bf16x8*)(pl0 + o);                       \
        (F).wl[1] = *(const bf16x8*)(pl1 + o);                       \
        (F).wr[0] = *(const bf16x8*)(pr0 + o);                       \
        (F).wr[1] = *(const bf16x8*)(pr1 + o);                       \
    } while (0)

#define L1_MFMA(F)                                                   \
    do {                                                             \
        _Pragma("unroll") for (int m = 0; m < 2; ++m)                \
            _Pragma("unroll") for (int n = 0; n < 2; ++n) {          \
            acc[m][n] = __builtin_amdgcn_mfma_f32_16x16x32_bf16(     \
                (F).a[m], (F).wl[n], acc[m][n], 0, 0, 0);            \
            acc[m][n] = __builtin_amdgcn_mfma_f32_16x16x32_bf16(     \
                (F).xx[m], (F).wr[n], acc[m][n], 0, 0, 0);           \
        }                                                            \
    } while (0)

    L1Frags f0, f1;
    L1_LOAD(f0, 0);
#pragma unroll
    for (int ks = 0; ks < 18; ks += 2) {
        L1_LOAD(f1, ks + 1);
        L1_MFMA(f0);
        L1_LOAD(f0, ks + 2);  // ks+2 <= 18 (kNT-1) in-range
        L1_MFMA(f1);
    }
    L1_MFMA(f0);  // ks = 18
#undef L1_LOAD
#undef L1_MFMA

    // C/D layout (validated R3-R5): col=lane&15, row=(lane>>4)*4+q
    const int col_l = lane & 15, rq = lane >> 4;
#pragma unroll
    for (int m = 0; m < 2; ++m)
#pragma unroll
        for (int n = 0; n < 2; ++n) {
            const int gc = jbase + n * 16 + col_l;
            const float bias = b1[gc];
#pragma unroll
            for (int q = 0; q < 4; ++q) {
                const int gr = mrow + m * 16 + rq * 4 + q;
                h[(size_t)gr * kHID + gc] = fmaxf(acc[m][n][q] + bias, 0.f);
            }
        }
}

// ---------------------------------------------------------------------------
// Layer 2 fused: gather-mean h[src2] rows (CSR, no atomics) + GEMV + row
// log_softmax. One wave per output node. (unchanged from R5)
// ---------------------------------------------------------------------------
__global__ __launch_bounds__(64)
void layer2_fused(const float* __restrict__ h, const int* __restrict__ off,
                  const int* __restrict__ ebuf, const float* __restrict__ W2l,
                  const float* __restrict__ W2r, const float* __restrict__ b2,
                  float* __restrict__ out) {
    __shared__ float sa[kHID];
    __shared__ float sh[kHID];
    const int n = blockIdx.x;
    const int t = threadIdx.x;
    const int b = off[n], e = off[n + 1];
    float ax = 0.f, ay = 0.f, az = 0.f, aw = 0.f;
    for (int i = b; i < e; ++i) {
        const float4 r = ((const float4*)(h + (size_t)ebuf[i] * kHID))[t];
        ax += r.x; ay += r.y; az += r.z; aw += r.w;
    }
    const float inv = 1.0f / fmaxf((float)(e - b), 1.0f);
    float4 o;
    o.x = ax * inv; o.y = ay * inv; o.z = az * inv; o.w = aw * inv;
    ((float4*)sa)[t] = o;
    ((float4*)sh)[t] = ((const float4*)(h + (size_t)n * kHID))[t];
    __syncthreads();

    float logit = 0.0f;
    if (t < kOUT) {
        logit = b2[t];
        for (int k = 0; k < kHID; ++k)
            logit += sa[k] * W2l[k * kOUT + t] + sh[k] * W2r[k * kOUT + t];
    }
    float m = (t < kOUT) ? logit : -INFINITY;
#pragma unroll
    for (int ofs = 32; ofs >= 1; ofs >>= 1)
        m = fmaxf(m, __shfl_xor(m, ofs));
    float ev = (t < kOUT) ? expf(logit - m) : 0.0f;
    float s = ev;
#pragma unroll
    for (int ofs = 32; ofs >= 1; ofs >>= 1)
        s += __shfl_xor(s, ofs);
    if (t < kOUT)
        out[(size_t)n * kOUT + t] = logit - m - logf(s);
}

// ---------------------------------------------------------------------------
extern "C" void kernel_launch(void* const* d_in, const int* in_sizes, int n_in,
                              void* d_out, int out_size, void* d_ws, size_t ws_size,
                              hipStream_t stream) {
    const float* x    = (const float*)d_in[0];
    const int*   src1 = (const int*)d_in[1];
    const int*   dst1 = (const int*)d_in[2];
    const int*   src2 = (const int*)d_in[3];
    const int*   dst2 = (const int*)d_in[4];
    const float* W1l  = (const float*)d_in[5];
    const float* W1r  = (const float*)d_in[6];
    const float* b1   = (const float*)d_in[7];
    const float* W2l  = (const float*)d_in[8];
    const float* W2r  = (const float*)d_in[9];
    const float* b2   = (const float*)d_in[10];
    float* out = (float*)d_out;

    // ---- workspace layout ----
    int* cnt1 = (int*)d_ws;                  // kN1
    int* cur1 = cnt1 + kN1;                  // kN1
    int* cnt2 = cur1 + kN1;                  // kN0
    int* cur2 = cnt2 + kN0;                  // kN0
    int* off1 = cur2 + kN0;                  // kN1 + 1
    int* off2 = off1 + kN1 + 1;              // kN0 + 1
    int* ebuf1 = off2 + kN0 + 1;             // kE1
    int* ebuf2 = ebuf1 + kE1;                // kE2
    size_t int_words = (size_t)2 * kN1 + 2 * kN0 + (kN1 + 1) + (kN0 + 1) + kE1 + kE2;
    int_words = (int_words + 7) & ~(size_t)7;  // 32B align

    ushort* aggb = (ushort*)((int*)d_ws + int_words);   // kN1*kKP bf16
    ushort* xb   = aggb + (size_t)kN1 * kKP;            // kN1*kKP
    ushort* wlt  = xb + (size_t)kN1 * kKP;              // kHID*kKP
    ushort* wrt  = wlt + (size_t)kHID * kKP;            // kHID*kKP
    float* h     = (float*)(wrt + (size_t)kHID * kKP);  // kN1*kHID fp32

    // zero histogram/cursor region (cnt1,cur1,cnt2,cur2 contiguous)
    hipMemsetAsync(cnt1, 0, ((size_t)2 * kN1 + 2 * kN0) * sizeof(int), stream);

    constexpr int EB = (kE1 + kE2 + 255) / 256;  // 700
    hist_both_kernel<<<EB, 256, 0, stream>>>(dst1, dst2, cnt1, cnt2);
    scan_both_kernel<<<2, 256, 0, stream>>>(cnt1, off1, cnt2, off2);
    bucket_both_kernel<<<EB, 256, 0, stream>>>(src1, dst1, off1, cur1, ebuf1,
                                               src2, dst2, off2, cur2, ebuf2);

    conv_x1_kernel<<<(kN1 * 304) / 256, 256, 0, stream>>>(x, xb);
    conv_w_both_kernel<<<512, 256, 0, stream>>>(W1l, W1r, wlt, wrt);

    aggregate1_kernel<<<kN1, 128, 0, stream>>>(x, off1, ebuf1, aggb);

    layer1_wave<<<(kN1 / 64) * 4, 256, 0, stream>>>(aggb, xb, wlt, wrt, b1, h);

    layer2_fused<<<kN0, 64, 0, stream>>>(h, off2, ebuf2, W2l, W2r, b2, out);
}

// Round 8
// 202.108 us; speedup vs baseline: 2.3920x; 1.0159x over previous
//
#include <hip/hip_runtime.h>
#include <hip/hip_bf16.h>
#include <math.h>

// Problem constants (from reference)
constexpr int kN2 = 180224, kN1 = 11264, kN0 = 1024;
constexpr int kE1 = 168960, kE2 = 10240;
constexpr int kIN = 602, kHID = 256, kOUT = 41;
constexpr int kKP = 608;  // kIN padded to multiple of 32 (MFMA K)

typedef __attribute__((ext_vector_type(8))) short bf16x8;
typedef __attribute__((ext_vector_type(4))) float f32x4;

static __device__ __forceinline__ ushort f2bf(float v) {
    return __bfloat16_as_ushort(__float2bfloat16(v));
}

// ---------------------------------------------------------------------------
// CSR build. hist -> (scan || W-convert) -> bucket.
// ---------------------------------------------------------------------------
__global__ __launch_bounds__(256)
void hist_both_kernel(const int* __restrict__ dst1, const int* __restrict__ dst2,
                      int* __restrict__ cnt1, int* __restrict__ cnt2) {
    const int gid = blockIdx.x * 256 + threadIdx.x;
    if (gid < kE1) {
        atomicAdd(&cnt1[dst1[gid]], 1);
    } else if (gid < kE1 + kE2) {
        atomicAdd(&cnt2[dst2[gid - kE1]], 1);
    }
}

// blocks 0,1: scan cnt->off for the two CSRs.
// blocks 2..513: convert+transpose W1l/W1r [602][256] -> [256][608] bf16
// (independent work folded in to overlap the 2-block scan latency bubble).
__global__ __launch_bounds__(256)
void scan_convw_kernel(const int* __restrict__ cnt1, int* __restrict__ off1,
                       const int* __restrict__ cnt2, int* __restrict__ off2,
                       const float* __restrict__ W1l, const float* __restrict__ W1r,
                       ushort* __restrict__ wlt, ushort* __restrict__ wrt) {
    const int t = threadIdx.x;
    if (blockIdx.x >= 2) {
        const int idx = blockIdx.x - 2;
        const int which = idx >> 8;
        const int j = idx & 255;
        const float* W = which ? W1r : W1l;
        ushort* Wt = which ? wrt : wlt;
        for (int k = t; k < kKP; k += 256) {
            float v = (k < kIN) ? W[(size_t)k * kHID + j] : 0.f;
            Wt[(size_t)j * kKP + k] = f2bf(v);
        }
        return;
    }
    __shared__ int part[256];
    const int* cnt = blockIdx.x ? cnt2 : cnt1;
    int* off = blockIdx.x ? off2 : off1;
    const int nN = blockIdx.x ? kN0 : kN1;
    const int CH = nN >> 8;
    const int base = t * CH;
    int s = 0;
    for (int i = 0; i < CH; ++i) s += cnt[base + i];
    part[t] = s;
    __syncthreads();
    for (int ofs = 1; ofs < 256; ofs <<= 1) {
        int v = (t >= ofs) ? part[t - ofs] : 0;
        __syncthreads();
        if (t >= ofs) part[t] += v;
        __syncthreads();
    }
    int run = (t == 0) ? 0 : part[t - 1];
    for (int i = 0; i < CH; ++i) {
        off[base + i] = run;
        run += cnt[base + i];
    }
    if (t == 255) off[nN] = run;
}

__global__ __launch_bounds__(256)
void bucket_both_kernel(const int* __restrict__ src1, const int* __restrict__ dst1,
                        const int* __restrict__ off1, int* __restrict__ cur1,
                        int* __restrict__ ebuf1,
                        const int* __restrict__ src2, const int* __restrict__ dst2,
                        const int* __restrict__ off2, int* __restrict__ cur2,
                        int* __restrict__ ebuf2) {
    const int gid = blockIdx.x * 256 + threadIdx.x;
    if (gid < kE1) {
        const int d = dst1[gid];
        const int p = atomicAdd(&cur1[d], 1);
        ebuf1[off1[d] + p] = src1[gid];
    } else if (gid < kE1 + kE2) {
        const int e = gid - kE1;
        const int d = dst2[e];
        const int p = atomicAdd(&cur2[d], 1);
        ebuf2[off2[d] + p] = src2[e];
    }
}

// ---------------------------------------------------------------------------
// Aggregation layer 1 + x[:N1] conversion fused. Block d:
//  (a) gather-mean x[src] rows into aggb[d] (float2 loads, 4-edge unroll for
//      12 row-loads in flight, fp32 accumulate, packed bf16 store)
//  (b) convert x[d] (d < kN1) into xb[d] (same 11264-block domain).
// ---------------------------------------------------------------------------
__global__ __launch_bounds__(128)
void aggregate1_kernel(const float* __restrict__ x, const int* __restrict__ off,
                       const int* __restrict__ ebuf, ushort* __restrict__ aggb,
                       ushort* __restrict__ xb) {
    const int d = blockIdx.x;
    const int t = threadIdx.x;
    const int b = off[d], e = off[d + 1];
    float p0x = 0.f, p0y = 0.f, p1x = 0.f, p1y = 0.f, p2x = 0.f, p2y = 0.f;
    float q0x = 0.f, q0y = 0.f, q1x = 0.f, q1y = 0.f, q2x = 0.f, q2y = 0.f;
    int i = b;
    for (; i + 4 <= e; i += 4) {
        const int s0 = ebuf[i], s1 = ebuf[i + 1];
        const int s2 = ebuf[i + 2], s3 = ebuf[i + 3];
        const float2* r0 = (const float2*)(x + (size_t)s0 * kIN);
        const float2* r1 = (const float2*)(x + (size_t)s1 * kIN);
        const float2* r2 = (const float2*)(x + (size_t)s2 * kIN);
        const float2* r3 = (const float2*)(x + (size_t)s3 * kIN);
        const float2 a0 = r0[t], a1 = r0[t + 128];
        const float2 b0 = r1[t], b1 = r1[t + 128];
        const float2 c0 = r2[t], c1 = r2[t + 128];
        const float2 d0 = r3[t], d1 = r3[t + 128];
        p0x += a0.x; p0y += a0.y; p1x += a1.x; p1y += a1.y;
        q0x += b0.x; q0y += b0.y; q1x += b1.x; q1y += b1.y;
        p0x += c0.x; p0y += c0.y; p1x += c1.x; p1y += c1.y;
        q0x += d0.x; q0y += d0.y; q1x += d1.x; q1y += d1.y;
        if (t < 45) {
            const float2 a2 = r0[t + 256], b2 = r1[t + 256];
            const float2 c2 = r2[t + 256], d2 = r3[t + 256];
            p2x += a2.x + c2.x; p2y += a2.y + c2.y;
            q2x += b2.x + d2.x; q2y += b2.y + d2.y;
        }
    }
    for (; i < e; ++i) {
        const int s0 = ebuf[i];
        const float2* r0 = (const float2*)(x + (size_t)s0 * kIN);
        const float2 a0 = r0[t], a1 = r0[t + 128];
        p0x += a0.x; p0y += a0.y; p1x += a1.x; p1y += a1.y;
        if (t < 45) {
            const float2 a2 = r0[t + 256];
            p2x += a2.x; p2y += a2.y;
        }
    }
    p0x += q0x; p0y += q0y; p1x += q1x; p1y += q1y; p2x += q2x; p2y += q2y;
    const float inv = 1.0f / fmaxf((float)(e - b), 1.0f);
    uint* ar = (uint*)(aggb + (size_t)d * kKP);  // 304 uints per row
    ar[t]       = (uint)f2bf(p0x * inv) | ((uint)f2bf(p0y * inv) << 16);
    ar[t + 128] = (uint)f2bf(p1x * inv) | ((uint)f2bf(p1y * inv) << 16);
    if (t < 45) ar[t + 256] = (uint)f2bf(p2x * inv) | ((uint)f2bf(p2y * inv) << 16);
    if (t >= 45 && t < 48) ar[t + 256] = 0u;  // zero pad shorts 602..607

    // (b) convert x row d -> xb row d
    const float2* xr = (const float2*)(x + (size_t)d * kIN);
    uint* xo = (uint*)(xb + (size_t)d * kKP);
#pragma unroll
    for (int u = t; u < 304; u += 128) {
        uint v = 0u;
        if (u < 301) {
            const float2 f = xr[u];
            v = (uint)f2bf(f.x) | ((uint)f2bf(f.y) << 16);
        }
        xo[u] = v;
    }
}

// ---------------------------------------------------------------------------
// Layer-1 GEMM: BARRIER-FREE per-wave MFMA. h = relu(agg@W1l + b1 + x@W1r).
// 64x128 block tile: 8 waves as 2x4 (each wave 32x32), 512 threads.
// Grid = 176 M-tiles x 2 N-tiles = 352 blocks (2816 waves, ~2.75/SIMD).
// Halves R7's VMEM traffic (A-pair read 2x instead of 4x, B-pair 176x ->
// from L2). Bijective XCD chunk swizzle (352 = 8*44) keeps both N-halves
// of an M-row in one XCD's L2 so A is HBM-fetched once.
// No LDS, no __syncthreads; depth-1 pipeline with named frag sets.
// ---------------------------------------------------------------------------
struct L1Frags {
    bf16x8 a[2];   // aggb rows m*16
    bf16x8 xx[2];  // xb rows
    bf16x8 wl[2];  // wlt rows n*16
    bf16x8 wr[2];  // wrt rows
};

__global__ __launch_bounds__(512)
void layer1_wave(const ushort* __restrict__ aggb, const ushort* __restrict__ xb,
                 const ushort* __restrict__ wlt, const ushort* __restrict__ wrt,
                 const float* __restrict__ b1, float* __restrict__ h) {
    const int t = threadIdx.x;
    const int lane = t & 63, wid = t >> 6;
    const int wr_ = wid >> 2, wc = wid & 3;        // 2x4 wave grid
    // XCD chunk swizzle: 352 blocks = 8 XCDs x 44
    const int bid = (int)(blockIdx.x & 7) * 44 + (int)(blockIdx.x >> 3);
    const int mt = bid >> 1, nt = bid & 1;
    const int mrow = mt * 64 + wr_ * 32;
    const int jbase = nt * 128 + wc * 32;

    const int rl = lane & 15;
    const int k8 = lane >> 4;

    // lane-constant base pointers (row*kKP + k8*8), rows 16B-aligned
    const ushort* pa0 = aggb + (size_t)(mrow + rl) * kKP + k8 * 8;
    const ushort* pa1 = pa0 + 16 * kKP;
    const ushort* px0 = xb + (size_t)(mrow + rl) * kKP + k8 * 8;
    const ushort* px1 = px0 + 16 * kKP;
    const ushort* pl0 = wlt + (size_t)(jbase + rl) * kKP + k8 * 8;
    const ushort* pl1 = pl0 + 16 * kKP;
    const ushort* pr0 = wrt + (size_t)(jbase + rl) * kKP + k8 * 8;
    const ushort* pr1 = pr0 + 16 * kKP;

    f32x4 acc[2][2];
#pragma unroll
    for (int m = 0; m < 2; ++m)
#pragma unroll
        for (int n = 0; n < 2; ++n) acc[m][n] = (f32x4){0.f, 0.f, 0.f, 0.f};

#define L1_LOAD(F, ks)                                               \
    do {                                                             \
        const int o = (ks) * 32;                                     \
        (F).a[0]  = *(const bf16x8*)(pa0 + o);                       \
        (F).a[1]  = *(const bf16x8*)(pa1 + o);                       \
        (F).xx[0] = *(const bf16x8*)(px0 + o);                       \
        (F).xx[1] = *(const bf16x8*)(px1 + o);                       \
        (F).wl[0] = *(const bf16x8*)(pl0 + o);                       \
        (F).wl[1] = *(const bf16x8*)(pl1 + o);                       \
        (F).wr[0] = *(const bf16x8*)(pr0 + o);                       \
        (F).wr[1] = *(const bf16x8*)(pr1 + o);                       \
    } while (0)

#define L1_MFMA(F)                                                   \
    do {                                                             \
        _Pragma("unroll") for (int m = 0; m < 2; ++m)                \
            _Pragma("unroll") for (int n = 0; n < 2; ++n) {          \
            acc[m][n] = __builtin_amdgcn_mfma_f32_16x16x32_bf16(     \
                (F).a[m], (F).wl[n], acc[m][n], 0, 0, 0);            \
            acc[m][n] = __builtin_amdgcn_mfma_f32_16x16x32_bf16(     \
                (F).xx[m], (F).wr[n], acc[m][n], 0, 0, 0);           \
        }                                                            \
    } while (0)

    L1Frags f0, f1;
    L1_LOAD(f0, 0);
#pragma unroll
    for (int ks = 0; ks < 18; ks += 2) {
        L1_LOAD(f1, ks + 1);
        L1_MFMA(f0);
        L1_LOAD(f0, ks + 2);  // ks+2 <= 18 (kNT-1) in-range
        L1_MFMA(f1);
    }
    L1_MFMA(f0);  // ks = 18
#undef L1_LOAD
#undef L1_MFMA

    // C/D layout (validated R3-R5): col=lane&15, row=(lane>>4)*4+q
    const int col_l = lane & 15, rq = lane >> 4;
#pragma unroll
    for (int m = 0; m < 2; ++m)
#pragma unroll
        for (int n = 0; n < 2; ++n) {
            const int gc = jbase + n * 16 + col_l;
            const float bias = b1[gc];
#pragma unroll
            for (int q = 0; q < 4; ++q) {
                const int gr = mrow + m * 16 + rq * 4 + q;
                h[(size_t)gr * kHID + gc] = fmaxf(acc[m][n][q] + bias, 0.f);
            }
        }
}

// ---------------------------------------------------------------------------
// Layer 2 fused: gather-mean h[src2] rows (CSR, no atomics) + GEMV + row
// log_softmax. One wave per output node.
// ---------------------------------------------------------------------------
__global__ __launch_bounds__(64)
void layer2_fused(const float* __restrict__ h, const int* __restrict__ off,
                  const int* __restrict__ ebuf, const float* __restrict__ W2l,
                  const float* __restrict__ W2r, const float* __restrict__ b2,
                  float* __restrict__ out) {
    __shared__ float sa[kHID];
    __shared__ float sh[kHID];
    const int n = blockIdx.x;
    const int t = threadIdx.x;
    const int b = off[n], e = off[n + 1];
    float ax = 0.f, ay = 0.f, az = 0.f, aw = 0.f;
    for (int i = b; i < e; ++i) {
        const float4 r = ((const float4*)(h + (size_t)ebuf[i] * kHID))[t];
        ax += r.x; ay += r.y; az += r.z; aw += r.w;
    }
    const float inv = 1.0f / fmaxf((float)(e - b), 1.0f);
    float4 o;
    o.x = ax * inv; o.y = ay * inv; o.z = az * inv; o.w = aw * inv;
    ((float4*)sa)[t] = o;
    ((float4*)sh)[t] = ((const float4*)(h + (size_t)n * kHID))[t];
    __syncthreads();

    float logit = 0.0f;
    if (t < kOUT) {
        logit = b2[t];
        for (int k = 0; k < kHID; ++k)
            logit += sa[k] * W2l[k * kOUT + t] + sh[k] * W2r[k * kOUT + t];
    }
    float m = (t < kOUT) ? logit : -INFINITY;
#pragma unroll
    for (int ofs = 32; ofs >= 1; ofs >>= 1)
        m = fmaxf(m, __shfl_xor(m, ofs));
    float ev = (t < kOUT) ? expf(logit - m) : 0.0f;
    float s = ev;
#pragma unroll
    for (int ofs = 32; ofs >= 1; ofs >>= 1)
        s += __shfl_xor(s, ofs);
    if (t < kOUT)
        out[(size_t)n * kOUT + t] = logit - m - logf(s);
}

// ---------------------------------------------------------------------------
extern "C" void kernel_launch(void* const* d_in, const int* in_sizes, int n_in,
                              void* d_out, int out_size, void* d_ws, size_t ws_size,
                              hipStream_t stream) {
    const float* x    = (const float*)d_in[0];
    const int*   src1 = (const int*)d_in[1];
    const int*   dst1 = (const int*)d_in[2];
    const int*   src2 = (const int*)d_in[3];
    const int*   dst2 = (const int*)d_in[4];
    const float* W1l  = (const float*)d_in[5];
    const float* W1r  = (const float*)d_in[6];
    const float* b1   = (const float*)d_in[7];
    const float* W2l  = (const float*)d_in[8];
    const float* W2r  = (const float*)d_in[9];
    const float* b2   = (const float*)d_in[10];
    float* out = (float*)d_out;

    // ---- workspace layout ----
    int* cnt1 = (int*)d_ws;                  // kN1
    int* cur1 = cnt1 + kN1;                  // kN1
    int* cnt2 = cur1 + kN1;                  // kN0
    int* cur2 = cnt2 + kN0;                  // kN0
    int* off1 = cur2 + kN0;                  // kN1 + 1
    int* off2 = off1 + kN1 + 1;              // kN0 + 1
    int* ebuf1 = off2 + kN0 + 1;             // kE1
    int* ebuf2 = ebuf1 + kE1;                // kE2
    size_t int_words = (size_t)2 * kN1 + 2 * kN0 + (kN1 + 1) + (kN0 + 1) + kE1 + kE2;
    int_words = (int_words + 7) & ~(size_t)7;  // 32B align

    ushort* aggb = (ushort*)((int*)d_ws + int_words);   // kN1*kKP bf16
    ushort* xb   = aggb + (size_t)kN1 * kKP;            // kN1*kKP
    ushort* wlt  = xb + (size_t)kN1 * kKP;              // kHID*kKP
    ushort* wrt  = wlt + (size_t)kHID * kKP;            // kHID*kKP
    float* h     = (float*)(wrt + (size_t)kHID * kKP);  // kN1*kHID fp32

    // zero histogram/cursor region (cnt1,cur1,cnt2,cur2 contiguous)
    hipMemsetAsync(cnt1, 0, ((size_t)2 * kN1 + 2 * kN0) * sizeof(int), stream);

    constexpr int EB = (kE1 + kE2 + 255) / 256;  // 700
    hist_both_kernel<<<EB, 256, 0, stream>>>(dst1, dst2, cnt1, cnt2);
    scan_convw_kernel<<<514, 256, 0, stream>>>(cnt1, off1, cnt2, off2,
                                               W1l, W1r, wlt, wrt);
    bucket_both_kernel<<<EB, 256, 0, stream>>>(src1, dst1, off1, cur1, ebuf1,
                                               src2, dst2, off2, cur2, ebuf2);

    aggregate1_kernel<<<kN1, 128, 0, stream>>>(x, off1, ebuf1, aggb, xb);

    layer1_wave<<<352, 512, 0, stream>>>(aggb, xb, wlt, wrt, b1, h);

    layer2_fused<<<kN0, 64, 0, stream>>>(h, off2, ebuf2, W2l, W2r, b2, out);
}